// Round 1
// baseline (1347.033 us; speedup 1.0000x reference)
//
#include <hip/hip_runtime.h>
#include <hip/hip_bf16.h>
#include <cstdint>

#define DIM   2048
#define MROWS 16384  // B*S = 8*2048

typedef __bf16 bf16x8 __attribute__((ext_vector_type(8)));
typedef float  f32x4  __attribute__((ext_vector_type(4)));
typedef unsigned short u16;
typedef unsigned int   u32;

// ---- ws layout (bytes), total 160 MiB ----
// [0,         25165824) : ternary bf16 Wf,Wc,Wg   (3 x 2048x2048 x 2B)
// [25165824,  33554432) : ternary bf16 Wo
// [33554432, 100663296) : x cast to bf16          (16384x2048 x 2B)
// [100663296,167772160) : gh = g*h bf16           (16384x2048 x 2B)

__device__ __forceinline__ u16 ternary_bits(float w) {
    u32 u = __float_as_uint(w);
    u16 s = (u16)((u >> 16) & 0x8000u);
    return (__builtin_fabsf(w) < 0.33f) ? (u16)0 : (u16)(0x3F80u | s);
}

__device__ __forceinline__ u16 f2bf_rne(float f) {
    u32 u = __float_as_uint(f);
    u32 r = (u + 0x7FFFu + ((u >> 16) & 1u)) >> 16;
    return (u16)r;
}

__device__ __forceinline__ void gload16(const void* g, void* l) {
    __builtin_amdgcn_global_load_lds(
        (const __attribute__((address_space(1))) void*)g,
        (__attribute__((address_space(3))) void*)l,
        16, 0, 0);
}

// ---------------- prep kernels ----------------

__global__ void prep_weights(const float* __restrict__ wf, const float* __restrict__ wc,
                             const float* __restrict__ wg, const float* __restrict__ wo,
                             u16* __restrict__ out) {
    const float* srcs[4] = {wf, wc, wg, wo};
    const float* src = srcs[blockIdx.y];
    u16* dst = out + (size_t)blockIdx.y * (DIM * DIM);
    int e = (blockIdx.x * 256 + threadIdx.x) * 8;
    float4 v0 = *(const float4*)(src + e);
    float4 v1 = *(const float4*)(src + e + 4);
    ushort4 o0, o1;
    o0.x = ternary_bits(v0.x); o0.y = ternary_bits(v0.y);
    o0.z = ternary_bits(v0.z); o0.w = ternary_bits(v0.w);
    o1.x = ternary_bits(v1.x); o1.y = ternary_bits(v1.y);
    o1.z = ternary_bits(v1.z); o1.w = ternary_bits(v1.w);
    *(ushort4*)(dst + e)     = o0;
    *(ushort4*)(dst + e + 4) = o1;
}

__global__ void cast_x(const float* __restrict__ x, u16* __restrict__ xb) {
    size_t e = ((size_t)blockIdx.x * 256 + threadIdx.x) * 8;
    float4 v0 = *(const float4*)(x + e);
    float4 v1 = *(const float4*)(x + e + 4);
    ushort4 o0, o1;
    o0.x = f2bf_rne(v0.x); o0.y = f2bf_rne(v0.y);
    o0.z = f2bf_rne(v0.z); o0.w = f2bf_rne(v0.w);
    o1.x = f2bf_rne(v1.x); o1.y = f2bf_rne(v1.y);
    o1.z = f2bf_rne(v1.z); o1.w = f2bf_rne(v1.w);
    *(ushort4*)(xb + e)     = o0;
    *(ushort4*)(xb + e + 4) = o1;
}

// ---------------- fused GEMM1: f/c/g preacts + activations + h + gh ----------------
// BM=128, BN=64, BK=64, 256 threads (4 waves, 2x2), wave tile 64x32 per matrix.

__global__ __launch_bounds__(256) void gemm1(
    const u16* __restrict__ xb,      // [16384][2048] bf16
    const u16* __restrict__ wt,      // [3][2048][2048] bf16 ternary (f,c,g)
    const float* __restrict__ bfv_, const float* __restrict__ bcv_, const float* __restrict__ bgv_,
    const float* __restrict__ hprev, // [16384][2048] f32
    float* __restrict__ hout,        // f32, second half of d_out
    u16* __restrict__ gh)            // bf16 ws
{
    __shared__ __align__(16) u16 sA[128 * 64];
    __shared__ __align__(16) u16 sB[3 * 64 * 64];

    const int tid  = threadIdx.x;
    const int lane = tid & 63;
    const int wave = tid >> 6;
    const int wr   = wave >> 1;  // 0..1
    const int wc   = wave & 1;   // 0..1
    const int brow = blockIdx.x * 128;
    const int bcol = blockIdx.y * 64;

    const int srow = tid >> 3;        // 0..31
    const int scol = (tid & 7) * 8;   // 0,8,..,56

    f32x4 acc[3][4][2] = {};

    for (int kt = 0; kt < DIM; kt += 64) {
        // stage A tile 128x64 (4 x 4KB)
        #pragma unroll
        for (int i = 0; i < 4; ++i) {
            const u16* src = xb + (size_t)(brow + i * 32 + srow) * DIM + kt + scol;
            u16* dst = sA + (i * 32 + srow) * 64 + scol;
            gload16(src, dst);
        }
        // stage B tiles 3 x 64x64 (2 x 4KB each)
        #pragma unroll
        for (int m = 0; m < 3; ++m) {
            #pragma unroll
            for (int i = 0; i < 2; ++i) {
                const u16* src = wt + (size_t)m * DIM * DIM + (size_t)(bcol + i * 32 + srow) * DIM + kt + scol;
                u16* dst = sB + m * 4096 + (i * 32 + srow) * 64 + scol;
                gload16(src, dst);
            }
        }
        __syncthreads();

        #pragma unroll
        for (int ks = 0; ks < 2; ++ks) {
            const int kof = ks * 32 + (lane >> 4) * 8;
            bf16x8 a[4];
            #pragma unroll
            for (int mi = 0; mi < 4; ++mi)
                a[mi] = *(const bf16x8*)(sA + (wr * 64 + mi * 16 + (lane & 15)) * 64 + kof);
            #pragma unroll
            for (int m = 0; m < 3; ++m) {
                #pragma unroll
                for (int ni = 0; ni < 2; ++ni) {
                    bf16x8 b = *(const bf16x8*)(sB + m * 4096 + (wc * 32 + ni * 16 + (lane & 15)) * 64 + kof);
                    #pragma unroll
                    for (int mi = 0; mi < 4; ++mi)
                        acc[m][mi][ni] = __builtin_amdgcn_mfma_f32_16x16x32_bf16(a[mi], b, acc[m][mi][ni], 0, 0, 0);
                }
            }
        }
        __syncthreads();
    }

    // fused epilogue: f=sigmoid, c=silu, g=sigmoid, h=f*hp+(1-f)*c, gh=g*h
    const int colbase = bcol + wc * 32 + (lane & 15);
    const int rowbase = brow + wr * 64 + ((lane >> 4) * 4);
    #pragma unroll
    for (int ni = 0; ni < 2; ++ni) {
        const int col = colbase + ni * 16;
        const float bfv = bfv_[col], bcv = bcv_[col], bgv = bgv_[col];
        #pragma unroll
        for (int mi = 0; mi < 4; ++mi) {
            #pragma unroll
            for (int j = 0; j < 4; ++j) {
                const int row = rowbase + mi * 16 + j;
                const size_t idx = (size_t)row * DIM + col;
                float pf = acc[0][mi][ni][j] + bfv;
                float pc = acc[1][mi][ni][j] + bcv;
                float pg = acc[2][mi][ni][j] + bgv;
                float f = 1.f / (1.f + __expf(-pf));
                float c = pc / (1.f + __expf(-pc));
                float g = 1.f / (1.f + __expf(-pg));
                float h = f * hprev[idx] + (1.f - f) * c;
                hout[idx] = h;
                gh[idx] = f2bf_rne(g * h);
            }
        }
    }
}

// ---------------- GEMM2: o = gh @ Wo^T + bo ----------------
// BM=128, BN=128, BK=64, 256 threads (4 waves 2x2), wave tile 64x64.

__global__ __launch_bounds__(256) void gemm2(
    const u16* __restrict__ gh,    // [16384][2048] bf16
    const u16* __restrict__ wot,   // [2048][2048] bf16 ternary
    const float* __restrict__ bov_,
    float* __restrict__ oout)      // f32, first half of d_out
{
    __shared__ __align__(16) u16 sA[128 * 64];
    __shared__ __align__(16) u16 sB[128 * 64];

    const int tid  = threadIdx.x;
    const int lane = tid & 63;
    const int wave = tid >> 6;
    const int wr   = wave >> 1;
    const int wc   = wave & 1;
    const int brow = blockIdx.x * 128;
    const int bcol = blockIdx.y * 128;

    const int srow = tid >> 3;
    const int scol = (tid & 7) * 8;

    f32x4 acc[4][4] = {};

    for (int kt = 0; kt < DIM; kt += 64) {
        #pragma unroll
        for (int i = 0; i < 4; ++i) {
            const u16* srcA = gh  + (size_t)(brow + i * 32 + srow) * DIM + kt + scol;
            const u16* srcB = wot + (size_t)(bcol + i * 32 + srow) * DIM + kt + scol;
            u16* dstA = sA + (i * 32 + srow) * 64 + scol;
            u16* dstB = sB + (i * 32 + srow) * 64 + scol;
            gload16(srcA, dstA);
            gload16(srcB, dstB);
        }
        __syncthreads();

        #pragma unroll
        for (int ks = 0; ks < 2; ++ks) {
            const int kof = ks * 32 + (lane >> 4) * 8;
            bf16x8 a[4], b[4];
            #pragma unroll
            for (int mi = 0; mi < 4; ++mi)
                a[mi] = *(const bf16x8*)(sA + (wr * 64 + mi * 16 + (lane & 15)) * 64 + kof);
            #pragma unroll
            for (int ni = 0; ni < 4; ++ni)
                b[ni] = *(const bf16x8*)(sB + (wc * 64 + ni * 16 + (lane & 15)) * 64 + kof);
            #pragma unroll
            for (int mi = 0; mi < 4; ++mi)
                #pragma unroll
                for (int ni = 0; ni < 4; ++ni)
                    acc[mi][ni] = __builtin_amdgcn_mfma_f32_16x16x32_bf16(a[mi], b[ni], acc[mi][ni], 0, 0, 0);
        }
        __syncthreads();
    }

    const int colbase = bcol + wc * 64 + (lane & 15);
    const int rowbase = brow + wr * 64 + ((lane >> 4) * 4);
    #pragma unroll
    for (int ni = 0; ni < 4; ++ni) {
        const int col = colbase + ni * 16;
        const float bov = bov_[col];
        #pragma unroll
        for (int mi = 0; mi < 4; ++mi) {
            #pragma unroll
            for (int j = 0; j < 4; ++j) {
                const int row = rowbase + mi * 16 + j;
                oout[(size_t)row * DIM + col] = acc[mi][ni][j] + bov;
            }
        }
    }
}

extern "C" void kernel_launch(void* const* d_in, const int* in_sizes, int n_in,
                              void* d_out, int out_size, void* d_ws, size_t ws_size,
                              hipStream_t stream) {
    const float* x  = (const float*)d_in[0];
    const float* hp = (const float*)d_in[1];
    const float* wf = (const float*)d_in[2];
    const float* bf = (const float*)d_in[3];
    const float* wc = (const float*)d_in[4];
    const float* bc = (const float*)d_in[5];
    const float* wg = (const float*)d_in[6];
    const float* bg = (const float*)d_in[7];
    const float* wo = (const float*)d_in[8];
    const float* bo = (const float*)d_in[9];

    float* o_out = (float*)d_out;
    float* h_out = o_out + (size_t)MROWS * DIM;

    u16* w_t  = (u16*)d_ws;                              // wf,wc,wg then wo
    u16* x_bf = (u16*)((char*)d_ws + 33554432);
    u16* gh   = (u16*)((char*)d_ws + 100663296);

    prep_weights<<<dim3(2048, 4), 256, 0, stream>>>(wf, wc, wg, wo, w_t);
    cast_x<<<dim3(16384), 256, 0, stream>>>(x, x_bf);
    gemm1<<<dim3(128, 32), 256, 0, stream>>>(x_bf, w_t, bf, bc, bg, hp, h_out, gh);
    gemm2<<<dim3(128, 16), 256, 0, stream>>>(gh, w_t + 3 * (size_t)DIM * DIM, bo, o_out);
}

// Round 2
// 956.831 us; speedup vs baseline: 1.4078x; 1.4078x over previous
//
#include <hip/hip_runtime.h>
#include <hip/hip_bf16.h>
#include <cstdint>

#define DIM   2048
#define MROWS 16384  // B*S = 8*2048

typedef __bf16 bf16x8 __attribute__((ext_vector_type(8)));
typedef float  f32x4  __attribute__((ext_vector_type(4)));
typedef unsigned short u16;
typedef unsigned int   u32;

// ---- ws layout (bytes), total 160 MiB ----
// [0,         25165824) : ternary bf16 Wf,Wc,Wg   (3 x 2048x2048 x 2B)
// [25165824,  33554432) : ternary bf16 Wo
// [33554432, 100663296) : x cast to bf16          (16384x2048 x 2B)
// [100663296,167772160) : gh = g*h bf16           (16384x2048 x 2B)

__device__ __forceinline__ u16 ternary_bits(float w) {
    u32 u = __float_as_uint(w);
    u16 s = (u16)((u >> 16) & 0x8000u);
    return (__builtin_fabsf(w) < 0.33f) ? (u16)0 : (u16)(0x3F80u | s);
}

__device__ __forceinline__ u16 f2bf_rne(float f) {
    u32 u = __float_as_uint(f);
    u32 r = (u + 0x7FFFu + ((u >> 16) & 1u)) >> 16;
    return (u16)r;
}

__device__ __forceinline__ void gload16(const void* g, void* l) {
    __builtin_amdgcn_global_load_lds(
        (const __attribute__((address_space(1))) void*)g,
        (__attribute__((address_space(3))) void*)l,
        16, 0, 0);
}

// ---------------- prep kernels ----------------

__global__ void prep_weights(const float* __restrict__ wf, const float* __restrict__ wc,
                             const float* __restrict__ wg, const float* __restrict__ wo,
                             u16* __restrict__ out) {
    const float* srcs[4] = {wf, wc, wg, wo};
    const float* src = srcs[blockIdx.y];
    u16* dst = out + (size_t)blockIdx.y * (DIM * DIM);
    int e = (blockIdx.x * 256 + threadIdx.x) * 8;
    float4 v0 = *(const float4*)(src + e);
    float4 v1 = *(const float4*)(src + e + 4);
    ushort4 o0, o1;
    o0.x = ternary_bits(v0.x); o0.y = ternary_bits(v0.y);
    o0.z = ternary_bits(v0.z); o0.w = ternary_bits(v0.w);
    o1.x = ternary_bits(v1.x); o1.y = ternary_bits(v1.y);
    o1.z = ternary_bits(v1.z); o1.w = ternary_bits(v1.w);
    *(ushort4*)(dst + e)     = o0;
    *(ushort4*)(dst + e + 4) = o1;
}

__global__ void cast_x(const float* __restrict__ x, u16* __restrict__ xb) {
    size_t e = ((size_t)blockIdx.x * 256 + threadIdx.x) * 8;
    float4 v0 = *(const float4*)(x + e);
    float4 v1 = *(const float4*)(x + e + 4);
    ushort4 o0, o1;
    o0.x = f2bf_rne(v0.x); o0.y = f2bf_rne(v0.y);
    o0.z = f2bf_rne(v0.z); o0.w = f2bf_rne(v0.w);
    o1.x = f2bf_rne(v1.x); o1.y = f2bf_rne(v1.y);
    o1.z = f2bf_rne(v1.z); o1.w = f2bf_rne(v1.w);
    *(ushort4*)(xb + e)     = o0;
    *(ushort4*)(xb + e + 4) = o1;
}

// ---------------- fused GEMM1: f/c/g preacts + activations + h + gh ----------------
// BM=128, BN=128 (per gate), BK=64, 512 threads (8 waves as 2x4), wave tile 64x32 per gate.
// LDS chunk-XOR swizzle: 16B chunk c at row r holds global chunk (c ^ (r&7)).
// Staged via linear global_load_lds dest + pre-swizzled global source (involution).

__global__ __launch_bounds__(512) void gemm1(
    const u16* __restrict__ xb,      // [16384][2048] bf16
    const u16* __restrict__ wt,      // [3][2048][2048] bf16 ternary (f,c,g)
    const float* __restrict__ bfv_, const float* __restrict__ bcv_, const float* __restrict__ bgv_,
    const float* __restrict__ hprev, // [16384][2048] f32
    float* __restrict__ hout,        // f32, second half of d_out
    u16* __restrict__ gh)            // bf16 ws
{
    __shared__ __align__(16) u16 sA[128 * 64];       // 16 KB
    __shared__ __align__(16) u16 sB[3 * 128 * 64];   // 48 KB

    const int tid  = threadIdx.x;
    const int lane = tid & 63;
    const int wave = tid >> 6;
    const int wr   = wave >> 2;  // 0..1 -> row half (64)
    const int wc   = wave & 3;   // 0..3 -> col quarter (32)
    const int brow = blockIdx.x * 128;
    const int bcol = blockIdx.y * 128;

    const int srow = tid >> 3;              // 0..63
    const int cg   = (tid & 7) ^ (srow & 7);  // swizzled source chunk
    const int sc_l = (tid & 7) * 8;           // linear LDS chunk offset (u16)

    f32x4 acc[3][4][2] = {};

    for (int kt = 0; kt < DIM; kt += 64) {
        // stage A 128x64: 2 passes of 64 rows
        #pragma unroll
        for (int i = 0; i < 2; ++i) {
            const u16* src = xb + (size_t)(brow + i * 64 + srow) * DIM + kt + cg * 8;
            u16* dst = sA + (i * 64 + srow) * 64 + sc_l;
            gload16(src, dst);
        }
        // stage B 3 x 128x64: 6 passes
        #pragma unroll
        for (int j = 0; j < 6; ++j) {
            const int m  = j >> 1;
            const int rl = (j & 1) * 64 + srow;
            const u16* src = wt + (size_t)m * DIM * DIM + (size_t)(bcol + rl) * DIM + kt + cg * 8;
            u16* dst = sB + m * 8192 + rl * 64 + sc_l;
            gload16(src, dst);
        }
        __syncthreads();

        #pragma unroll
        for (int ks = 0; ks < 2; ++ks) {
            const int hi = lane >> 4;
            const int cs = ((ks * 4 + hi) ^ (lane & 7)) * 8;  // swizzled read chunk (u16)
            bf16x8 a[4];
            #pragma unroll
            for (int mi = 0; mi < 4; ++mi) {
                const int ra = wr * 64 + mi * 16 + (lane & 15);
                a[mi] = *(const bf16x8*)(sA + ra * 64 + cs);
            }
            #pragma unroll
            for (int m = 0; m < 3; ++m) {
                #pragma unroll
                for (int ni = 0; ni < 2; ++ni) {
                    const int rb = wc * 32 + ni * 16 + (lane & 15);
                    bf16x8 b = *(const bf16x8*)(sB + m * 8192 + rb * 64 + cs);
                    #pragma unroll
                    for (int mi = 0; mi < 4; ++mi)
                        acc[m][mi][ni] = __builtin_amdgcn_mfma_f32_16x16x32_bf16(a[mi], b, acc[m][mi][ni], 0, 0, 0);
                }
            }
        }
        __syncthreads();
    }

    // fused epilogue: f=sigmoid, c=silu, g=sigmoid, h=f*hp+(1-f)*c, gh=g*h
    const int colbase = bcol + wc * 32 + (lane & 15);
    const int rowbase = brow + wr * 64 + ((lane >> 4) * 4);
    #pragma unroll
    for (int ni = 0; ni < 2; ++ni) {
        const int col = colbase + ni * 16;
        const float bfv = bfv_[col], bcv = bcv_[col], bgv = bgv_[col];
        #pragma unroll
        for (int mi = 0; mi < 4; ++mi) {
            #pragma unroll
            for (int j = 0; j < 4; ++j) {
                const int row = rowbase + mi * 16 + j;
                const size_t idx = (size_t)row * DIM + col;
                float pf = acc[0][mi][ni][j] + bfv;
                float pc = acc[1][mi][ni][j] + bcv;
                float pg = acc[2][mi][ni][j] + bgv;
                float f = 1.f / (1.f + __expf(-pf));
                float c = pc / (1.f + __expf(-pc));
                float g = 1.f / (1.f + __expf(-pg));
                float h = f * hprev[idx] + (1.f - f) * c;
                hout[idx] = h;
                gh[idx] = f2bf_rne(g * h);
            }
        }
    }
}

// ---------------- GEMM2: o = gh @ Wo^T + bo ----------------
// BM=128, BN=128, BK=64, 256 threads (4 waves 2x2), wave tile 64x64. Swizzled LDS.

__global__ __launch_bounds__(256) void gemm2(
    const u16* __restrict__ gh,    // [16384][2048] bf16
    const u16* __restrict__ wot,   // [2048][2048] bf16 ternary
    const float* __restrict__ bov_,
    float* __restrict__ oout)      // f32, first half of d_out
{
    __shared__ __align__(16) u16 sA[128 * 64];
    __shared__ __align__(16) u16 sB[128 * 64];

    const int tid  = threadIdx.x;
    const int lane = tid & 63;
    const int wave = tid >> 6;
    const int wr   = wave >> 1;
    const int wc   = wave & 1;
    const int brow = blockIdx.x * 128;
    const int bcol = blockIdx.y * 128;

    const int srow = tid >> 3;                // 0..31
    const int cg   = (tid & 7) ^ (srow & 7);  // swizzled source chunk
    const int sc_l = (tid & 7) * 8;

    f32x4 acc[4][4] = {};

    for (int kt = 0; kt < DIM; kt += 64) {
        #pragma unroll
        for (int i = 0; i < 4; ++i) {
            const int rl = i * 32 + srow;
            const u16* srcA = gh  + (size_t)(brow + rl) * DIM + kt + cg * 8;
            const u16* srcB = wot + (size_t)(bcol + rl) * DIM + kt + cg * 8;
            gload16(srcA, sA + rl * 64 + sc_l);
            gload16(srcB, sB + rl * 64 + sc_l);
        }
        __syncthreads();

        #pragma unroll
        for (int ks = 0; ks < 2; ++ks) {
            const int hi = lane >> 4;
            const int cs = ((ks * 4 + hi) ^ (lane & 7)) * 8;
            bf16x8 a[4], b[4];
            #pragma unroll
            for (int mi = 0; mi < 4; ++mi)
                a[mi] = *(const bf16x8*)(sA + (wr * 64 + mi * 16 + (lane & 15)) * 64 + cs);
            #pragma unroll
            for (int ni = 0; ni < 4; ++ni)
                b[ni] = *(const bf16x8*)(sB + (wc * 64 + ni * 16 + (lane & 15)) * 64 + cs);
            #pragma unroll
            for (int mi = 0; mi < 4; ++mi)
                #pragma unroll
                for (int ni = 0; ni < 4; ++ni)
                    acc[mi][ni] = __builtin_amdgcn_mfma_f32_16x16x32_bf16(a[mi], b[ni], acc[mi][ni], 0, 0, 0);
        }
        __syncthreads();
    }

    const int colbase = bcol + wc * 64 + (lane & 15);
    const int rowbase = brow + wr * 64 + ((lane >> 4) * 4);
    #pragma unroll
    for (int ni = 0; ni < 4; ++ni) {
        const int col = colbase + ni * 16;
        const float bov = bov_[col];
        #pragma unroll
        for (int mi = 0; mi < 4; ++mi) {
            #pragma unroll
            for (int j = 0; j < 4; ++j) {
                const int row = rowbase + mi * 16 + j;
                oout[(size_t)row * DIM + col] = acc[mi][ni][j] + bov;
            }
        }
    }
}

extern "C" void kernel_launch(void* const* d_in, const int* in_sizes, int n_in,
                              void* d_out, int out_size, void* d_ws, size_t ws_size,
                              hipStream_t stream) {
    const float* x  = (const float*)d_in[0];
    const float* hp = (const float*)d_in[1];
    const float* wf = (const float*)d_in[2];
    const float* bf = (const float*)d_in[3];
    const float* wc = (const float*)d_in[4];
    const float* bc = (const float*)d_in[5];
    const float* wg = (const float*)d_in[6];
    const float* bg = (const float*)d_in[7];
    const float* wo = (const float*)d_in[8];
    const float* bo = (const float*)d_in[9];

    float* o_out = (float*)d_out;
    float* h_out = o_out + (size_t)MROWS * DIM;

    u16* w_t  = (u16*)d_ws;                              // wf,wc,wg then wo
    u16* x_bf = (u16*)((char*)d_ws + 33554432);
    u16* gh   = (u16*)((char*)d_ws + 100663296);

    prep_weights<<<dim3(2048, 4), 256, 0, stream>>>(wf, wc, wg, wo, w_t);
    cast_x<<<dim3(16384), 256, 0, stream>>>(x, x_bf);
    gemm1<<<dim3(128, 16), 512, 0, stream>>>(x_bf, w_t, bf, bc, bg, hp, h_out, gh);
    gemm2<<<dim3(128, 16), 256, 0, stream>>>(gh, w_t + 3 * (size_t)DIM * DIM, bo, o_out);
}

// Round 3
// 831.473 us; speedup vs baseline: 1.6201x; 1.1508x over previous
//
#include <hip/hip_runtime.h>
#include <hip/hip_bf16.h>
#include <cstdint>

#define DIM   2048
#define MROWS 16384  // B*S = 8*2048

typedef __bf16 bf16x8 __attribute__((ext_vector_type(8)));
typedef float  f32x4  __attribute__((ext_vector_type(4)));
typedef unsigned short u16;
typedef unsigned int   u32;

// ---- ws layout (bytes), total 160 MiB ----
// [0,         25165824) : ternary bf16 Wf,Wc,Wg   (3 x 2048x2048 x 2B)
// [25165824,  33554432) : ternary bf16 Wo
// [33554432, 100663296) : x cast to bf16          (16384x2048 x 2B)
// [100663296,167772160) : gh = g*h bf16           (16384x2048 x 2B)

__device__ __forceinline__ u16 ternary_bits(float w) {
    u32 u = __float_as_uint(w);
    u16 s = (u16)((u >> 16) & 0x8000u);
    return (__builtin_fabsf(w) < 0.33f) ? (u16)0 : (u16)(0x3F80u | s);
}

__device__ __forceinline__ u16 f2bf_rne(float f) {
    u32 u = __float_as_uint(f);
    u32 r = (u + 0x7FFFu + ((u >> 16) & 1u)) >> 16;
    return (u16)r;
}

__device__ __forceinline__ void gload16(const void* g, void* l) {
    __builtin_amdgcn_global_load_lds(
        (const __attribute__((address_space(1))) void*)g,
        (__attribute__((address_space(3))) void*)l,
        16, 0, 0);
}

// ---------------- prep kernels ----------------

__global__ void prep_weights(const float* __restrict__ wf, const float* __restrict__ wc,
                             const float* __restrict__ wg, const float* __restrict__ wo,
                             u16* __restrict__ out) {
    const float* srcs[4] = {wf, wc, wg, wo};
    const float* src = srcs[blockIdx.y];
    u16* dst = out + (size_t)blockIdx.y * (DIM * DIM);
    int e = (blockIdx.x * 256 + threadIdx.x) * 8;
    float4 v0 = *(const float4*)(src + e);
    float4 v1 = *(const float4*)(src + e + 4);
    ushort4 o0, o1;
    o0.x = ternary_bits(v0.x); o0.y = ternary_bits(v0.y);
    o0.z = ternary_bits(v0.z); o0.w = ternary_bits(v0.w);
    o1.x = ternary_bits(v1.x); o1.y = ternary_bits(v1.y);
    o1.z = ternary_bits(v1.z); o1.w = ternary_bits(v1.w);
    *(ushort4*)(dst + e)     = o0;
    *(ushort4*)(dst + e + 4) = o1;
}

__global__ void cast_x(const float* __restrict__ x, u16* __restrict__ xb) {
    size_t e = ((size_t)blockIdx.x * 256 + threadIdx.x) * 8;
    float4 v0 = *(const float4*)(x + e);
    float4 v1 = *(const float4*)(x + e + 4);
    ushort4 o0, o1;
    o0.x = f2bf_rne(v0.x); o0.y = f2bf_rne(v0.y);
    o0.z = f2bf_rne(v0.z); o0.w = f2bf_rne(v0.w);
    o1.x = f2bf_rne(v1.x); o1.y = f2bf_rne(v1.y);
    o1.z = f2bf_rne(v1.z); o1.w = f2bf_rne(v1.w);
    *(ushort4*)(xb + e)     = o0;
    *(ushort4*)(xb + e + 4) = o1;
}

// ---------------- fused GEMM1: f/c/g preacts + activations + h + gh ----------------
// BM=128, BN=128 (per gate), BK=64, 512 threads (8 waves as 2x4), wave tile 64x32/gate.
// Double-buffered LDS, stage-next-before-compute, one sync per K-tile (T3 minimum).
// LDS chunk-XOR swizzle (T2): linear gload_lds dest + pre-swizzled global source.
// XCD-contiguous grid swizzle (T1): 2048 blocks = 8 x 256.

__global__ __launch_bounds__(512) void gemm1(
    const u16* __restrict__ xb,      // [16384][2048] bf16
    const u16* __restrict__ wt,      // [3][2048][2048] bf16 ternary (f,c,g)
    const float* __restrict__ bfv_, const float* __restrict__ bcv_, const float* __restrict__ bgv_,
    const float* __restrict__ hprev, // [16384][2048] f32
    float* __restrict__ hout,        // f32, second half of d_out
    u16* __restrict__ gh)            // bf16 ws
{
    __shared__ __align__(16) u16 sA[2][128 * 64];       // 2 x 16 KB
    __shared__ __align__(16) u16 sB[2][3 * 128 * 64];   // 2 x 48 KB

    const int tid  = threadIdx.x;
    const int lane = tid & 63;
    const int wave = tid >> 6;
    const int wr   = wave >> 2;  // 0..1 -> row half (64)
    const int wc   = wave & 3;   // 0..3 -> col quarter (32)

    const int bid  = blockIdx.x;
    const int swz  = (bid & 7) * 256 + (bid >> 3);   // XCD-contiguous chunks
    const int brow = (swz & 127) * 128;              // m-tile fast within chunk
    const int bcol = (swz >> 7) * 128;

    const int srow = tid >> 3;                // 0..63
    const int cg   = (tid & 7) ^ (srow & 7);  // swizzled source chunk
    const int sc_l = (tid & 7) * 8;           // linear LDS chunk offset (u16)

    f32x4 acc[3][4][2] = {};

    auto stage = [&](int buf, int kt) {
        #pragma unroll
        for (int i = 0; i < 2; ++i) {
            const u16* src = xb + (size_t)(brow + i * 64 + srow) * DIM + kt + cg * 8;
            gload16(src, &sA[buf][(i * 64 + srow) * 64 + sc_l]);
        }
        #pragma unroll
        for (int j = 0; j < 6; ++j) {
            const int m  = j >> 1;
            const int rl = (j & 1) * 64 + srow;
            const u16* src = wt + (size_t)m * DIM * DIM + (size_t)(bcol + rl) * DIM + kt + cg * 8;
            gload16(src, &sB[buf][m * 8192 + rl * 64 + sc_l]);
        }
    };

    stage(0, 0);
    __syncthreads();     // vmcnt(0) drain + barrier: buf0 ready

    int cur = 0;
    for (int kt = 0; kt < DIM; kt += 64) {
        if (kt + 64 < DIM) stage(cur ^ 1, kt + 64);   // async prefetch, other buffer

        const u16* lA = &sA[cur][0];
        const u16* lB = &sB[cur][0];
        #pragma unroll
        for (int ks = 0; ks < 2; ++ks) {
            const int hi = lane >> 4;
            const int cs = ((ks * 4 + hi) ^ (lane & 7)) * 8;  // swizzled read chunk (u16)
            bf16x8 a[4];
            #pragma unroll
            for (int mi = 0; mi < 4; ++mi) {
                const int ra = wr * 64 + mi * 16 + (lane & 15);
                a[mi] = *(const bf16x8*)(lA + ra * 64 + cs);
            }
            __builtin_amdgcn_s_setprio(1);
            #pragma unroll
            for (int m = 0; m < 3; ++m) {
                #pragma unroll
                for (int ni = 0; ni < 2; ++ni) {
                    const int rb = wc * 32 + ni * 16 + (lane & 15);
                    bf16x8 b = *(const bf16x8*)(lB + m * 8192 + rb * 64 + cs);
                    #pragma unroll
                    for (int mi = 0; mi < 4; ++mi)
                        acc[m][mi][ni] = __builtin_amdgcn_mfma_f32_16x16x32_bf16(a[mi], b, acc[m][mi][ni], 0, 0, 0);
                }
            }
            __builtin_amdgcn_s_setprio(0);
        }
        __syncthreads();   // drains prefetch vmcnt(0) + all reads of cur done
        cur ^= 1;
    }

    // fused epilogue: f=sigmoid, c=silu, g=sigmoid, h=f*hp+(1-f)*c, gh=g*h
    const int colbase = bcol + wc * 32 + (lane & 15);
    const int rowbase = brow + wr * 64 + ((lane >> 4) * 4);
    #pragma unroll
    for (int ni = 0; ni < 2; ++ni) {
        const int col = colbase + ni * 16;
        const float bfv = bfv_[col], bcv = bcv_[col], bgv = bgv_[col];
        #pragma unroll
        for (int mi = 0; mi < 4; ++mi) {
            #pragma unroll
            for (int j = 0; j < 4; ++j) {
                const int row = rowbase + mi * 16 + j;
                const size_t idx = (size_t)row * DIM + col;
                float pf = acc[0][mi][ni][j] + bfv;
                float pc = acc[1][mi][ni][j] + bcv;
                float pg = acc[2][mi][ni][j] + bgv;
                float f = 1.f / (1.f + __expf(-pf));
                float c = pc / (1.f + __expf(-pc));
                float g = 1.f / (1.f + __expf(-pg));
                float h = f * hprev[idx] + (1.f - f) * c;
                hout[idx] = h;
                gh[idx] = f2bf_rne(g * h);
            }
        }
    }
}

// ---------------- GEMM2: o = gh @ Wo^T + bo ----------------
// BM=128, BN=128, BK=64, 256 threads (4 waves 2x2), wave tile 64x64.
// Double-buffered, swizzled, XCD-contiguous grid.

__global__ __launch_bounds__(256) void gemm2(
    const u16* __restrict__ gh,    // [16384][2048] bf16
    const u16* __restrict__ wot,   // [2048][2048] bf16 ternary
    const float* __restrict__ bov_,
    float* __restrict__ oout)      // f32, first half of d_out
{
    __shared__ __align__(16) u16 sA[2][128 * 64];
    __shared__ __align__(16) u16 sB[2][128 * 64];

    const int tid  = threadIdx.x;
    const int lane = tid & 63;
    const int wave = tid >> 6;
    const int wr   = wave >> 1;
    const int wc   = wave & 1;

    const int bid  = blockIdx.x;
    const int swz  = (bid & 7) * 256 + (bid >> 3);
    const int brow = (swz & 127) * 128;
    const int bcol = (swz >> 7) * 128;

    const int srow = tid >> 3;                // 0..31
    const int cg   = (tid & 7) ^ (srow & 7);  // swizzled source chunk
    const int sc_l = (tid & 7) * 8;

    f32x4 acc[4][4] = {};

    auto stage = [&](int buf, int kt) {
        #pragma unroll
        for (int i = 0; i < 4; ++i) {
            const int rl = i * 32 + srow;
            const u16* srcA = gh  + (size_t)(brow + rl) * DIM + kt + cg * 8;
            const u16* srcB = wot + (size_t)(bcol + rl) * DIM + kt + cg * 8;
            gload16(srcA, &sA[buf][rl * 64 + sc_l]);
            gload16(srcB, &sB[buf][rl * 64 + sc_l]);
        }
    };

    stage(0, 0);
    __syncthreads();

    int cur = 0;
    for (int kt = 0; kt < DIM; kt += 64) {
        if (kt + 64 < DIM) stage(cur ^ 1, kt + 64);

        const u16* lA = &sA[cur][0];
        const u16* lB = &sB[cur][0];
        #pragma unroll
        for (int ks = 0; ks < 2; ++ks) {
            const int hi = lane >> 4;
            const int cs = ((ks * 4 + hi) ^ (lane & 7)) * 8;
            bf16x8 a[4], b[4];
            #pragma unroll
            for (int mi = 0; mi < 4; ++mi)
                a[mi] = *(const bf16x8*)(lA + (wr * 64 + mi * 16 + (lane & 15)) * 64 + cs);
            #pragma unroll
            for (int ni = 0; ni < 4; ++ni)
                b[ni] = *(const bf16x8*)(lB + (wc * 64 + ni * 16 + (lane & 15)) * 64 + cs);
            __builtin_amdgcn_s_setprio(1);
            #pragma unroll
            for (int mi = 0; mi < 4; ++mi)
                #pragma unroll
                for (int ni = 0; ni < 4; ++ni)
                    acc[mi][ni] = __builtin_amdgcn_mfma_f32_16x16x32_bf16(a[mi], b[ni], acc[mi][ni], 0, 0, 0);
            __builtin_amdgcn_s_setprio(0);
        }
        __syncthreads();
        cur ^= 1;
    }

    const int colbase = bcol + wc * 64 + (lane & 15);
    const int rowbase = brow + wr * 64 + ((lane >> 4) * 4);
    #pragma unroll
    for (int ni = 0; ni < 4; ++ni) {
        const int col = colbase + ni * 16;
        const float bov = bov_[col];
        #pragma unroll
        for (int mi = 0; mi < 4; ++mi) {
            #pragma unroll
            for (int j = 0; j < 4; ++j) {
                const int row = rowbase + mi * 16 + j;
                oout[(size_t)row * DIM + col] = acc[mi][ni][j] + bov;
            }
        }
    }
}

extern "C" void kernel_launch(void* const* d_in, const int* in_sizes, int n_in,
                              void* d_out, int out_size, void* d_ws, size_t ws_size,
                              hipStream_t stream) {
    const float* x  = (const float*)d_in[0];
    const float* hp = (const float*)d_in[1];
    const float* wf = (const float*)d_in[2];
    const float* bf = (const float*)d_in[3];
    const float* wc = (const float*)d_in[4];
    const float* bc = (const float*)d_in[5];
    const float* wg = (const float*)d_in[6];
    const float* bg = (const float*)d_in[7];
    const float* wo = (const float*)d_in[8];
    const float* bo = (const float*)d_in[9];

    float* o_out = (float*)d_out;
    float* h_out = o_out + (size_t)MROWS * DIM;

    u16* w_t  = (u16*)d_ws;                              // wf,wc,wg then wo
    u16* x_bf = (u16*)((char*)d_ws + 33554432);
    u16* gh   = (u16*)((char*)d_ws + 100663296);

    prep_weights<<<dim3(2048, 4), 256, 0, stream>>>(wf, wc, wg, wo, w_t);
    cast_x<<<dim3(16384), 256, 0, stream>>>(x, x_bf);
    gemm1<<<dim3(2048), 512, 0, stream>>>(x_bf, w_t, bf, bc, bg, hp, h_out, gh);
    gemm2<<<dim3(2048), 256, 0, stream>>>(gh, w_t + 3 * (size_t)DIM * DIM, bo, o_out);
}

// Round 5
// 801.746 us; speedup vs baseline: 1.6801x; 1.0371x over previous
//
#include <hip/hip_runtime.h>
#include <hip/hip_bf16.h>
#include <cstdint>

#define DIM   2048
#define MROWS 16384  // B*S = 8*2048
#define NT    32     // K tiles of 64

typedef __bf16 bf16x8 __attribute__((ext_vector_type(8)));
typedef float  f32x4  __attribute__((ext_vector_type(4)));
typedef unsigned short u16;
typedef unsigned int   u32;

#define BARRIER() asm volatile("s_barrier" ::: "memory")
#define WAITVM(N) asm volatile("s_waitcnt vmcnt(" #N ")" ::: "memory")

// ---- ws layout (bytes), total 160 MiB ----
// [0,         25165824) : ternary bf16 Wf,Wc,Wg   (3 x 2048x2048 x 2B)
// [25165824,  33554432) : ternary bf16 Wo
// [33554432, 100663296) : x cast to bf16          (16384x2048 x 2B)
// [100663296,167772160) : gh = g*h bf16           (16384x2048 x 2B)

__device__ __forceinline__ u16 ternary_bits(float w) {
    u32 u = __float_as_uint(w);
    u16 s = (u16)((u >> 16) & 0x8000u);
    return (__builtin_fabsf(w) < 0.33f) ? (u16)0 : (u16)(0x3F80u | s);
}

__device__ __forceinline__ u16 f2bf_rne(float f) {
    u32 u = __float_as_uint(f);
    u32 r = (u + 0x7FFFu + ((u >> 16) & 1u)) >> 16;
    return (u16)r;
}

__device__ __forceinline__ void gload16(const void* g, void* l) {
    __builtin_amdgcn_global_load_lds(
        (const __attribute__((address_space(1))) void*)g,
        (__attribute__((address_space(3))) void*)l,
        16, 0, 0);
}

// ---------------- prep kernels ----------------

__global__ void prep_weights(const float* __restrict__ wf, const float* __restrict__ wc,
                             const float* __restrict__ wg, const float* __restrict__ wo,
                             u16* __restrict__ out) {
    const float* srcs[4] = {wf, wc, wg, wo};
    const float* src = srcs[blockIdx.y];
    u16* dst = out + (size_t)blockIdx.y * (DIM * DIM);
    int e = (blockIdx.x * 256 + threadIdx.x) * 8;
    float4 v0 = *(const float4*)(src + e);
    float4 v1 = *(const float4*)(src + e + 4);
    ushort4 o0, o1;
    o0.x = ternary_bits(v0.x); o0.y = ternary_bits(v0.y);
    o0.z = ternary_bits(v0.z); o0.w = ternary_bits(v0.w);
    o1.x = ternary_bits(v1.x); o1.y = ternary_bits(v1.y);
    o1.z = ternary_bits(v1.z); o1.w = ternary_bits(v1.w);
    *(ushort4*)(dst + e)     = o0;
    *(ushort4*)(dst + e + 4) = o1;
}

__global__ void cast_x(const float* __restrict__ x, u16* __restrict__ xb) {
    size_t e = ((size_t)blockIdx.x * 256 + threadIdx.x) * 8;
    float4 v0 = *(const float4*)(x + e);
    float4 v1 = *(const float4*)(x + e + 4);
    ushort4 o0, o1;
    o0.x = f2bf_rne(v0.x); o0.y = f2bf_rne(v0.y);
    o0.z = f2bf_rne(v0.z); o0.w = f2bf_rne(v0.w);
    o1.x = f2bf_rne(v1.x); o1.y = f2bf_rne(v1.y);
    o1.z = f2bf_rne(v1.z); o1.w = f2bf_rne(v1.w);
    *(ushort4*)(xb + e)     = o0;
    *(ushort4*)(xb + e + 4) = o1;
}

// ---------------- fused GEMM1: f/c/g preacts + activations + h + gh ----------------
// BM=128, BN=128 (x3 gates), BK=64, 512 thr (8 waves 2x4), wave tile 64x32/gate.
// LDS layout: [buf][ks-half][row 0..127][32 k] u16 — each stage pass fills one
// 8KB half LINEARLY in tid (gload_lds HW writes base+lane*16, rule #21/m104).
// Bank swizzle: 16B chunk cs = kchunk ^ ((row>>1)&3), applied on the global
// SOURCE at stage time and on the ds_read address (involution).
// 4-phase counted-vmcnt pipeline: 2 loads/phase for tile T+1 during tile T,
// WAITVM(4) at p1 (validates tile-T ks1) and p3 (validates tile-T+1 ks0).

__global__ __launch_bounds__(512) void gemm1(
    const u16* __restrict__ xb,      // [16384][2048] bf16
    const u16* __restrict__ wt,      // [3][2048][2048] bf16 ternary (f,c,g)
    const float* __restrict__ bfv_, const float* __restrict__ bcv_, const float* __restrict__ bgv_,
    const float* __restrict__ hprev, // [16384][2048] f32
    float* __restrict__ hout,        // f32, second half of d_out
    u16* __restrict__ gh)            // bf16 ws
{
    __shared__ __align__(16) u16 sA[2][2][128 * 32];      // 32 KB
    __shared__ __align__(16) u16 sB[2][2][3][128 * 32];   // 96 KB

    const int tid  = threadIdx.x;
    const int lane = tid & 63;
    const int wave = tid >> 6;
    const int wr   = wave >> 2;   // 0..1
    const int wcq  = wave & 3;    // 0..3

    const int bid  = blockIdx.x;
    const int swz  = (bid & 7) * 256 + (bid >> 3);   // XCD-contiguous chunks
    const int brow = (swz & 127) * 128;
    const int bcol = (swz >> 7) * 128;

    // staging: thread tid -> LDS u16 offset tid*8 within an 8KB half (linear),
    // fetches global row (tid>>2), 16B chunk gc4 (source-swizzled)
    const int row512 = tid >> 2;                      // 0..127
    const int gc4    = (tid & 3) ^ ((tid >> 3) & 3);  // swizzled source chunk
    const int ldst   = tid * 8;                       // u16 offset in half

    const int fr  = lane & 15;
    const int hi  = lane >> 4;                        // 0..3
    const int csw = (hi ^ ((fr >> 1) & 3)) * 8;       // swizzled read chunk (u16)

    f32x4 acc0[3][4] = {};   // ni = 0
    f32x4 acc1[3][4] = {};   // ni = 1

    const u16* aSrc  = xb + (size_t)(brow + row512) * DIM;
    const u16* bSrc0 = wt + (size_t)(bcol + row512) * DIM;
    const size_t WSTRIDE = (size_t)DIM * DIM;

    auto issueA = [&](int buf, int kt, int ks) {
        gload16(aSrc + kt + ks * 32 + gc4 * 8, (u16*)&sA[buf][ks][ldst]);
    };
    auto issueB = [&](int buf, int kt, int g, int ks) {
        gload16(bSrc0 + (size_t)g * WSTRIDE + kt + ks * 32 + gc4 * 8,
                (u16*)&sB[buf][ks][g][ldst]);
    };

    auto rdA = [&](const u16* lA, int ks, bf16x8 (&a)[4]) {
        #pragma unroll
        for (int mi = 0; mi < 4; ++mi)
            a[mi] = *(const bf16x8*)(lA + ks * 4096 + (wr * 64 + mi * 16 + fr) * 32 + csw);
    };
    auto rdB = [&](const u16* lB, int ks, int ni, bf16x8 (&b)[3]) {
        #pragma unroll
        for (int g = 0; g < 3; ++g)
            b[g] = *(const bf16x8*)(lB + ks * 12288 + g * 4096 + (wcq * 32 + ni * 16 + fr) * 32 + csw);
    };
    auto domfma = [&](bf16x8 (&a)[4], bf16x8 (&b)[3], f32x4 (&c)[3][4]) {
        __builtin_amdgcn_s_setprio(1);
        #pragma unroll
        for (int g = 0; g < 3; ++g)
            #pragma unroll
            for (int mi = 0; mi < 4; ++mi)
                c[g][mi] = __builtin_amdgcn_mfma_f32_16x16x32_bf16(a[mi], b[g], c[g][mi], 0, 0, 0);
        __builtin_amdgcn_s_setprio(0);
    };

    // prologue: stage tile 0 fully, drain once
    issueA(0, 0, 0); issueB(0, 0, 0, 0);
    issueB(0, 0, 1, 0); issueB(0, 0, 2, 0);
    issueA(0, 0, 1); issueB(0, 0, 0, 1);
    issueB(0, 0, 1, 1); issueB(0, 0, 2, 1);
    WAITVM(0);
    BARRIER();

    #pragma unroll 1
    for (int t = 0; t < NT - 1; ++t) {
        const u16* lA = &sA[t & 1][0][0];
        const u16* lB = &sB[t & 1][0][0][0];
        const int nb = (t + 1) & 1;
        const int kn = (t + 1) * 64;
        bf16x8 a[4], b[3];
        // p0 (ks0, ni0)
        rdA(lA, 0, a); rdB(lB, 0, 0, b);
        issueA(nb, kn, 0); issueB(nb, kn, 0, 0);
        BARRIER();
        domfma(a, b, acc0);
        BARRIER();
        // p1 (ks0, ni1)
        rdB(lB, 0, 1, b);
        issueB(nb, kn, 1, 0); issueB(nb, kn, 2, 0);
        WAITVM(4);           // retires tile-T ks1 loads -> p2/p3 region valid
        BARRIER();
        domfma(a, b, acc1);
        BARRIER();
        // p2 (ks1, ni0)
        rdA(lA, 1, a); rdB(lB, 1, 0, b);
        issueA(nb, kn, 1); issueB(nb, kn, 0, 1);
        BARRIER();
        domfma(a, b, acc0);
        BARRIER();
        // p3 (ks1, ni1)
        rdB(lB, 1, 1, b);
        issueB(nb, kn, 1, 1); issueB(nb, kn, 2, 1);
        WAITVM(4);           // retires tile-(T+1) ks0 loads -> next p0 region valid
        BARRIER();
        domfma(a, b, acc1);
        BARRIER();
    }
    { // final tile (buf 1), no issues; drain remaining ks1 loads at p1
        const u16* lA = &sA[1][0][0];
        const u16* lB = &sB[1][0][0][0];
        bf16x8 a[4], b[3];
        rdA(lA, 0, a); rdB(lB, 0, 0, b);
        BARRIER(); domfma(a, b, acc0); BARRIER();
        rdB(lB, 0, 1, b);
        WAITVM(0);
        BARRIER(); domfma(a, b, acc1); BARRIER();
        rdA(lA, 1, a); rdB(lB, 1, 0, b);
        BARRIER(); domfma(a, b, acc0); BARRIER();
        rdB(lB, 1, 1, b);
        domfma(a, b, acc1);
    }

    // fused epilogue
    auto epi = [&](int ni, f32x4 (&c)[3][4]) {
        const int col = bcol + wcq * 32 + ni * 16 + fr;
        const float bfv = bfv_[col], bcv = bcv_[col], bgv = bgv_[col];
        #pragma unroll
        for (int mi = 0; mi < 4; ++mi) {
            #pragma unroll
            for (int j = 0; j < 4; ++j) {
                const int row = brow + wr * 64 + mi * 16 + hi * 4 + j;
                const size_t idx = (size_t)row * DIM + col;
                float pf = c[0][mi][j] + bfv;
                float pc = c[1][mi][j] + bcv;
                float pg = c[2][mi][j] + bgv;
                float f  = 1.f / (1.f + __expf(-pf));
                float cc = pc / (1.f + __expf(-pc));
                float g  = 1.f / (1.f + __expf(-pg));
                float h  = f * hprev[idx] + (1.f - f) * cc;
                hout[idx] = h;
                gh[idx] = f2bf_rne(g * h);
            }
        }
    };
    epi(0, acc0);
    epi(1, acc1);
}

// ---------------- GEMM2: o = gh @ Wo^T + bo ----------------
// BM=128, BN=256, BK=64, 512 thr (8 waves 2x4), wave tile 64x64.
// Same layout/schedule; 6 loads/tile -> WAITVM(4) @p1, WAITVM(3) @p3.
// LDS B half = 256 rows x 32 k (16KB) filled by two linear passes (lo/hi rows).

__global__ __launch_bounds__(512) void gemm2(
    const u16* __restrict__ gh,    // [16384][2048] bf16
    const u16* __restrict__ wot,   // [2048][2048] bf16 ternary
    const float* __restrict__ bov_,
    float* __restrict__ oout)      // f32, first half of d_out
{
    __shared__ __align__(16) u16 sA[2][2][128 * 32];   // 32 KB
    __shared__ __align__(16) u16 sB[2][2][256 * 32];   // 64 KB

    const int tid  = threadIdx.x;
    const int lane = tid & 63;
    const int wave = tid >> 6;
    const int wr   = wave >> 2;   // 0..1
    const int wcq  = wave & 3;    // 0..3

    const int bid  = blockIdx.x;                     // 1024 blocks = 128 m x 8 n
    const int swz  = (bid & 7) * 128 + (bid >> 3);
    const int brow = (swz & 127) * 128;
    const int bcol = (swz >> 7) * 256;

    const int row512 = tid >> 2;
    const int gc4    = (tid & 3) ^ ((tid >> 3) & 3);
    const int ldst   = tid * 8;

    const int fr  = lane & 15;
    const int hi  = lane >> 4;
    const int csw = (hi ^ ((fr >> 1) & 3)) * 8;

    f32x4 accL[4][2] = {};   // ni 0..1
    f32x4 accH[4][2] = {};   // ni 2..3

    const u16* aSrc  = gh  + (size_t)(brow + row512) * DIM;
    const u16* bSrcL = wot + (size_t)(bcol + row512) * DIM;
    const u16* bSrcH = wot + (size_t)(bcol + 128 + row512) * DIM;

    auto issueA = [&](int buf, int kt, int ks) {
        gload16(aSrc + kt + ks * 32 + gc4 * 8, (u16*)&sA[buf][ks][ldst]);
    };
    auto issueBlo = [&](int buf, int kt, int ks) {
        gload16(bSrcL + kt + ks * 32 + gc4 * 8, (u16*)&sB[buf][ks][ldst]);
    };
    auto issueBhi = [&](int buf, int kt, int ks) {
        gload16(bSrcH + kt + ks * 32 + gc4 * 8, (u16*)&sB[buf][ks][4096 + ldst]);
    };

    auto rdA = [&](const u16* lA, int ks, bf16x8 (&a)[4]) {
        #pragma unroll
        for (int mi = 0; mi < 4; ++mi)
            a[mi] = *(const bf16x8*)(lA + ks * 4096 + (wr * 64 + mi * 16 + fr) * 32 + csw);
    };
    auto rdB2 = [&](const u16* lB, int ks, int nbase, bf16x8 (&b)[2]) {
        #pragma unroll
        for (int jn = 0; jn < 2; ++jn)
            b[jn] = *(const bf16x8*)(lB + ks * 8192 + (wcq * 64 + (nbase + jn) * 16 + fr) * 32 + csw);
    };
    auto domfma2 = [&](bf16x8 (&a)[4], bf16x8 (&b)[2], f32x4 (&c)[4][2]) {
        __builtin_amdgcn_s_setprio(1);
        #pragma unroll
        for (int jn = 0; jn < 2; ++jn)
            #pragma unroll
            for (int mi = 0; mi < 4; ++mi)
                c[mi][jn] = __builtin_amdgcn_mfma_f32_16x16x32_bf16(a[mi], b[jn], c[mi][jn], 0, 0, 0);
        __builtin_amdgcn_s_setprio(0);
    };

    // prologue: tile 0
    issueA(0, 0, 0); issueBlo(0, 0, 0);
    issueBhi(0, 0, 0); issueA(0, 0, 1);
    issueBlo(0, 0, 1);
    issueBhi(0, 0, 1);
    WAITVM(0);
    BARRIER();

    #pragma unroll 1
    for (int t = 0; t < NT - 1; ++t) {
        const u16* lA = &sA[t & 1][0][0];
        const u16* lB = &sB[t & 1][0][0];
        const int nb = (t + 1) & 1;
        const int kn = (t + 1) * 64;
        bf16x8 a[4], b[2];
        // p0 (ks0, ni 0-1)
        rdA(lA, 0, a); rdB2(lB, 0, 0, b);
        issueA(nb, kn, 0); issueBlo(nb, kn, 0);
        BARRIER();
        domfma2(a, b, accL);
        BARRIER();
        // p1 (ks0, ni 2-3)
        rdB2(lB, 0, 2, b);
        issueBhi(nb, kn, 0); issueA(nb, kn, 1);
        WAITVM(4);           // retires tile-T ks1 loads (3)
        BARRIER();
        domfma2(a, b, accH);
        BARRIER();
        // p2 (ks1, ni 0-1)
        rdA(lA, 1, a); rdB2(lB, 1, 0, b);
        issueBlo(nb, kn, 1);
        BARRIER();
        domfma2(a, b, accL);
        BARRIER();
        // p3 (ks1, ni 2-3)
        rdB2(lB, 1, 2, b);
        issueBhi(nb, kn, 1);
        WAITVM(3);           // retires tile-(T+1) ks0 loads (3)
        BARRIER();
        domfma2(a, b, accH);
        BARRIER();
    }
    { // final tile (buf 1)
        const u16* lA = &sA[1][0][0];
        const u16* lB = &sB[1][0][0];
        bf16x8 a[4], b[2];
        rdA(lA, 0, a); rdB2(lB, 0, 0, b);
        BARRIER(); domfma2(a, b, accL); BARRIER();
        rdB2(lB, 0, 2, b);
        WAITVM(0);
        BARRIER(); domfma2(a, b, accH); BARRIER();
        rdA(lA, 1, a); rdB2(lB, 1, 0, b);
        BARRIER(); domfma2(a, b, accL); BARRIER();
        rdB2(lB, 1, 2, b);
        domfma2(a, b, accH);
    }

    auto epi2 = [&](int nbase, f32x4 (&c)[4][2]) {
        #pragma unroll
        for (int jn = 0; jn < 2; ++jn) {
            const int col = bcol + wcq * 64 + (nbase + jn) * 16 + fr;
            const float bov = bov_[col];
            #pragma unroll
            for (int mi = 0; mi < 4; ++mi)
                #pragma unroll
                for (int j = 0; j < 4; ++j)
                    oout[(size_t)(brow + wr * 64 + mi * 16 + hi * 4 + j) * DIM + col] = c[mi][jn][j] + bov;
        }
    };
    epi2(0, accL);
    epi2(2, accH);
}

extern "C" void kernel_launch(void* const* d_in, const int* in_sizes, int n_in,
                              void* d_out, int out_size, void* d_ws, size_t ws_size,
                              hipStream_t stream) {
    const float* x  = (const float*)d_in[0];
    const float* hp = (const float*)d_in[1];
    const float* wf = (const float*)d_in[2];
    const float* bf = (const float*)d_in[3];
    const float* wc = (const float*)d_in[4];
    const float* bc = (const float*)d_in[5];
    const float* wg = (const float*)d_in[6];
    const float* bg = (const float*)d_in[7];
    const float* wo = (const float*)d_in[8];
    const float* bo = (const float*)d_in[9];

    float* o_out = (float*)d_out;
    float* h_out = o_out + (size_t)MROWS * DIM;

    u16* w_t  = (u16*)d_ws;                              // wf,wc,wg then wo
    u16* x_bf = (u16*)((char*)d_ws + 33554432);
    u16* gh   = (u16*)((char*)d_ws + 100663296);

    prep_weights<<<dim3(2048, 4), 256, 0, stream>>>(wf, wc, wg, wo, w_t);
    cast_x<<<dim3(16384), 256, 0, stream>>>(x, x_bf);
    gemm1<<<dim3(2048), 512, 0, stream>>>(x_bf, w_t, bf, bc, bg, hp, h_out, gh);
    gemm2<<<dim3(1024), 512, 0, stream>>>(gh, w_t + 3 * (size_t)DIM * DIM, bo, o_out);
}